// Round 8
// baseline (698.791 us; speedup 1.0000x reference)
//
#include <hip/hip_runtime.h>

// GRU4REC v5: MFMA, 2 independent blocks/CU to fill barrier/latency bubbles.
// B=1024, T=256, D=64, H=128.
// 512 blocks x 256 threads (4 waves), 2 rows/block (M-pad to 16), 2 blocks/CU.
// Wave w owns gate n-tile pairs {w,w+8},{w+4,w+12} and cand tiles {w,w+4}:
// r,u,c,h for cols [16*(w+4ct),+16) live in lanes 0..15 (C: col=lane, row=reg).
// Weights persist as B-fragments: 36 half8 = 144 regs/thread; MFMA operands
// may live in AGPRs (unified file) -> no scratch spill at 256-reg budget
// (R7 evidence); v_dot2 variants (R5/R6) spilled because VOP3P can't use AGPR.
// LDS: fp16 A-operands [x|h],[x|r*h] only, 416 B row stride.

#define T_   256
#define D_   64
#define H_   128
#define SROW 208   // halves per A-row (416 B)

typedef _Float16 half8_t  __attribute__((ext_vector_type(8)));
typedef float    floatx4  __attribute__((ext_vector_type(4)));

__global__ __launch_bounds__(256, 2) void gru_mfma2(
    const int* __restrict__ item_his,          // [1024][256]
    const int* __restrict__ seq_lens,          // [1024]
    const float* __restrict__ emb,             // [1e6][64]
    const float* __restrict__ Wg,              // [192][256]
    const float* __restrict__ bg,              // [256]
    const float* __restrict__ Wc,              // [192][128]
    const float* __restrict__ bc,              // [128]
    float* __restrict__ out)                   // [1024][128] fp32
{
    __shared__ __align__(16) _Float16 XA[16][SROW];  // [x | h]   (gate A)
    __shared__ __align__(16) _Float16 XC[16][SROW];  // [x | r*h] (cand A)

    const int tid  = threadIdx.x;
    const int w    = tid >> 6;        // wave 0..3
    const int lane = tid & 63;
    const int row0 = blockIdx.x * 2;

    // ---- persistent B-fragments ----
    // B-frag (K32xN16): lane holds B[k = kt*32 + (lane>>4)*8 + i][n = lane&15]
    const int bq = lane >> 4;
    const int bn = lane & 15;
    half8_t BR[2][6], BU[2][6], BCf[2][6];   // r-gate, u-gate, cand per col-tile
    #pragma unroll
    for (int ct = 0; ct < 2; ++ct) {
        const int colg = (w + 4 * ct) * 16 + bn;
        #pragma unroll
        for (int kt = 0; kt < 6; ++kt) {
            half8_t fr, fu, fc;
            #pragma unroll
            for (int i = 0; i < 8; ++i) {
                const int k = kt * 32 + bq * 8 + i;
                fr[i] = (_Float16)Wg[k * 256 + colg];
                fu[i] = (_Float16)Wg[k * 256 + 128 + colg];
                fc[i] = (_Float16)Wc[k * 128 + colg];
            }
            BR[ct][kt] = fr; BU[ct][kt] = fu; BCf[ct][kt] = fc;
        }
    }

    float bgR[2], bgU[2], bcC[2];
    #pragma unroll
    for (int ct = 0; ct < 2; ++ct) {
        const int colg = (w + 4 * ct) * 16 + bn;
        bgR[ct] = bg[colg];
        bgU[ct] = bg[128 + colg];
        bcC[ct] = bc[colg];
    }

    int len[2];
    len[0] = seq_lens[row0 + 0];
    len[1] = seq_lens[row0 + 1];
    const int maxlen = max(len[0], len[1]);

    // ---- zero A-buffers (rows 2..15 stay zero forever) ----
    {
        unsigned* pa = (unsigned*)&XA[0][0];
        unsigned* pc = (unsigned*)&XC[0][0];
        for (int i = tid; i < 16 * SROW / 2; i += 256) { pa[i] = 0u; pc[i] = 0u; }
    }
    __syncthreads();

    // ---- x-gather: tid<128 covers 2 rows x 64 dims ----
    const bool ldr   = (tid < 128);
    const int  row_l = tid >> 6;    // 0..1
    const int  d_l   = tid & 63;

    float xprev = 0.f;
    if (ldr && maxlen > 0) {
        const int idx = item_his[(row0 + row_l) * T_ + 0];
        xprev = emb[(size_t)idx * D_ + d_l];
        const _Float16 xh = (_Float16)xprev;
        XA[row_l][d_l] = xh;
        XC[row_l][d_l] = xh;
    }
    float h[2][2] = {{0.f, 0.f}, {0.f, 0.f}};
    float u[2][2] = {{0.f, 0.f}, {0.f, 0.f}};
    __syncthreads();

    for (int t = 0; t < maxlen; ++t) {
        // ================= Phase 1: gate =================
        if (ldr) XC[row_l][d_l] = (_Float16)xprev;        // x_t for cand
        float xnew = 0.f;
        if (ldr) {                                         // prefetch x_{t+1}
            const int idx = item_his[(row0 + row_l) * T_ + (t + 1)];
            xnew = emb[(size_t)idx * D_ + d_l];
        }

        floatx4 aR[2] = {{0.f,0.f,0.f,0.f},{0.f,0.f,0.f,0.f}};
        floatx4 aU[2] = {{0.f,0.f,0.f,0.f},{0.f,0.f,0.f,0.f}};
        #pragma unroll
        for (int kt = 0; kt < 6; ++kt) {
            const half8_t af = *(const half8_t*)&XA[bn][kt * 32 + bq * 8];
            aR[0] = __builtin_amdgcn_mfma_f32_16x16x32_f16(af, BR[0][kt], aR[0], 0, 0, 0);
            aU[0] = __builtin_amdgcn_mfma_f32_16x16x32_f16(af, BU[0][kt], aU[0], 0, 0, 0);
            aR[1] = __builtin_amdgcn_mfma_f32_16x16x32_f16(af, BR[1][kt], aR[1], 0, 0, 0);
            aU[1] = __builtin_amdgcn_mfma_f32_16x16x32_f16(af, BU[1][kt], aU[1], 0, 0, 0);
        }
        // valid rows 0..1 -> lanes 0..15, reg r
        if (lane < 16) {
            #pragma unroll
            for (int ct = 0; ct < 2; ++ct) {
                #pragma unroll
                for (int r = 0; r < 2; ++r) {
                    const float rg = 1.f / (1.f + __expf(-(aR[ct][r] + bgR[ct])));
                    u[r][ct]       = 1.f / (1.f + __expf(-(aU[ct][r] + bgU[ct])));
                    XC[r][64 + (w + 4 * ct) * 16 + lane] = (_Float16)(rg * h[r][ct]);
                }
            }
        }
        __syncthreads();

        // ================= Phase 2: cand + h update =================
        if (ldr) XA[row_l][d_l] = (_Float16)xnew;          // x_{t+1} for gate

        floatx4 aC[2] = {{0.f,0.f,0.f,0.f},{0.f,0.f,0.f,0.f}};
        #pragma unroll
        for (int kt = 0; kt < 6; ++kt) {
            const half8_t af = *(const half8_t*)&XC[bn][kt * 32 + bq * 8];
            aC[0] = __builtin_amdgcn_mfma_f32_16x16x32_f16(af, BCf[0][kt], aC[0], 0, 0, 0);
            aC[1] = __builtin_amdgcn_mfma_f32_16x16x32_f16(af, BCf[1][kt], aC[1], 0, 0, 0);
        }
        if (lane < 16) {
            #pragma unroll
            for (int ct = 0; ct < 2; ++ct) {
                #pragma unroll
                for (int r = 0; r < 2; ++r) {
                    float s = aC[ct][r] + bcC[ct];
                    s = fminf(fmaxf(s, -15.f), 15.f);
                    const float e = __expf(2.f * s);
                    const float c = (e - 1.f) / (e + 1.f);      // tanh
                    const float hn = u[r][ct] * h[r][ct] + (1.f - u[r][ct]) * c;
                    if (t < len[r]) h[r][ct] = hn;              // copy-through
                    XA[r][64 + (w + 4 * ct) * 16 + lane] = (_Float16)h[r][ct];
                }
            }
        }
        xprev = xnew;
        __syncthreads();
    }

    // ---- write final h (fp32) ----
    if (lane < 16) {
        #pragma unroll
        for (int ct = 0; ct < 2; ++ct)
            #pragma unroll
            for (int r = 0; r < 2; ++r)
                out[(row0 + r) * H_ + (w + 4 * ct) * 16 + lane] = h[r][ct];
    }
}

extern "C" void kernel_launch(void* const* d_in, const int* in_sizes, int n_in,
                              void* d_out, int out_size, void* d_ws, size_t ws_size,
                              hipStream_t stream) {
    const int*   item_his = (const int*)d_in[0];
    const int*   seq_lens = (const int*)d_in[1];
    const float* emb      = (const float*)d_in[2];
    const float* Wg       = (const float*)d_in[3];
    const float* bg       = (const float*)d_in[4];
    const float* Wc       = (const float*)d_in[5];
    const float* bc       = (const float*)d_in[6];
    float*       out      = (float*)d_out;

    gru_mfma2<<<512, 256, 0, stream>>>(item_his, seq_lens, emb, Wg, bg, Wc, bc, out);
}